// Round 3
// baseline (1028.484 us; speedup 1.0000x reference)
//
#include <hip/hip_runtime.h>
#include <cstdint>
#include <cstddef>

// Problem constants
#define B_   2
#define P_   8192
#define NN_  24
#define C1_  32
#define C2_  32
#define K_   13
#define A_   12
#define DR_  384   // rows: d*12+r
#define CA_  384   // cols: c*12+a
#define PT_  64    // p-tile per block
#define BPAD 408   // 384+24: row stride 204 dw == 12 mod 32 -> 2-way (free) b128 reads

typedef __attribute__((ext_vector_type(8))) short short8;
typedef __attribute__((ext_vector_type(4))) float floatx4;

__device__ __forceinline__ unsigned short f2bf(float f) {
    union { float f; unsigned int u; } v; v.f = f;
    unsigned int u = v.u;
    return (unsigned short)((u + 0x7fffu + ((u >> 16) & 1u)) >> 16); // RNE
}

// ---------------- prep kernels ----------------

// WT2[k][dr][ca] = bf16( W[d,c,m] * k_pos_w[d,m] ), row-major (768 B rows).
__global__ void build_wt(const float* __restrict__ W, const float* __restrict__ kpw,
                         const int* __restrict__ idx_map, const int* __restrict__ tivr,
                         const int* __restrict__ tir, unsigned short* __restrict__ WT2) {
    int id = blockIdx.x * 256 + threadIdx.x;
    const int TOT = K_ * DR_ * CA_;
    if (id >= TOT) return;
    int ca = id % CA_;
    int t1 = id / CA_;
    int dr = t1 % DR_;
    int k  = t1 / DR_;
    int d = dr / 12, r = dr % 12;
    int c = ca / 12, a = ca % 12;
    int kk = tivr[r * K_ + k];
    int ia = tir[r * A_ + a];
    int m  = idx_map[kk * A_ + ia];
    WT2[id] = f2bf(W[(d * C1_ + c) * 36 + m] * kpw[d * 36 + m]);
}

__global__ void build_md(const int* __restrict__ nbr, const float* __restrict__ verts,
                         float* __restrict__ md) {
    int t = blockIdx.x * 256 + threadIdx.x;
    if (t >= B_ * P_) return;
    const float* vp = verts + (size_t)t * 3;
    float vx = vp[0], vy = vp[1], vz = vp[2];
    int b = t / P_;
    const int* np = nbr + (size_t)t * NN_;
    float ax = 0.f, ay = 0.f, az = 0.f;
    for (int n = 0; n < NN_; n++) {
        int j = np[n];
        const float* vq = verts + ((size_t)b * P_ + j) * 3;
        float dx = vq[0] - vx, dy = vq[1] - vy, dz = vq[2] - vz;
        float nn = sqrtf(dx * dx + dy * dy + dz * dz);
        float inv = 1.f / fmaxf(nn, 1e-12f);
        ax += dx * inv; ay += dy * inv; az += dz * inv;
    }
    const float s = 1.f / 24.f;
    md[t * 3 + 0] = ax * s; md[t * 3 + 1] = ay * s; md[t * 3 + 2] = az * s;
}

__global__ void build_kpo(const float* __restrict__ kpw, const int* __restrict__ idx_map,
                          const float* __restrict__ vs, float* __restrict__ kpo) {
    int t = blockIdx.x * 64 + threadIdx.x;
    if (t >= C2_ * K_) return;
    int d = t / K_, k = t % K_;
    float x = 0.f, y = 0.f, z = 0.f;
    for (int a = 0; a < A_; a++) {
        float w = kpw[d * 36 + idx_map[k * A_ + a]];
        x += w * vs[a * 3 + 0]; y += w * vs[a * 3 + 1]; z += w * vs[a * 3 + 2];
    }
    float nn = sqrtf(x * x + y * y + z * z);
    float inv = 1.f / fmaxf(nn, 1e-12f);
    kpo[t * 3 + 0] = x * inv; kpo[t * 3 + 1] = y * inv; kpo[t * 3 + 2] = z * inv;
}

__global__ void build_be(const float* __restrict__ bias, const int* __restrict__ lvl,
                         const int* __restrict__ tivr, float* __restrict__ be) {
    int t = blockIdx.x * 64 + threadIdx.x;
    if (t >= DR_) return;
    int d = t / 12, r = t % 12;
    float s = 0.f;
    for (int k = 0; k < K_; k++) s += bias[d * 5 + lvl[tivr[r * K_ + k]]];
    be[t] = s;
}

// ---------------- main fused kernel ----------------
// grid = 256 blocks (b x 128 p-tiles of 64), 512 threads = 8 waves, 1 block/CU.
// Waves 0-5: consumers (64 dr x 64 p each; WT from global L2, fm never).
// Waves 6-7: producers (stream fm slice k+1 -> Bs bf16, compute pw) — their
// vmcnt drains are wave-private and never stall the MFMA waves.
__global__ __launch_bounds__(512, 2) void main_gemm(
    const float* __restrict__ fm, const unsigned short* __restrict__ WT,
    const float* __restrict__ md, const float* __restrict__ kpo,
    const float* __restrict__ be, float* __restrict__ out) {

    __shared__ __attribute__((aligned(16))) unsigned short Bs[2][PT_][BPAD]; // 104448 B
    __shared__ float pwS[2][PT_][33];      // +1 pad: kills 16-way bank conflict. 16896 B
    __shared__ float mdS[PT_][3];          // 768 B
    __shared__ float kpoS[C2_ * K_ * 3];   // 4992 B
    __shared__ float biasS[DR_];           // 1536 B

    const int tid  = threadIdx.x;
    const int bid  = blockIdx.x;
    const int b    = bid >> 7;
    const int p0   = (bid & 127) << 6;
    const int lane = tid & 63;
    const int wid  = tid >> 6;
    const int rowm = lane & 15;
    const int quad = lane >> 4;
    const bool consumer = (wid < 6);

    // ---- producer macros: fm slice s (64p x 384ca f32) -> Bs[bw] bf16, in 4 rounds
    // fi = rr*1536 + jj*128 + ptid ; c = fi/192 ; j = fi%192 ; p = j/3 ; a4 = (j%3)*4
    #define PLOADR(dst, s, rr)                                                           \
        { _Pragma("unroll")                                                              \
          for (int jj = 0; jj < 12; jj++) {                                              \
            int fi = (rr) * 1536 + jj * 128 + ptid;                                      \
            int c = fi / 192; int j = fi - c * 192;                                      \
            dst[jj] = *((const float4*)(fm +                                             \
                ((((size_t)b * C1_ + c) * K_ + (s)) * P_ + p0) * A_) + j);               \
          } }
    #define PWRITE(src, bw, rr)                                                          \
        { _Pragma("unroll")                                                              \
          for (int jj = 0; jj < 12; jj++) {                                              \
            int fi = (rr) * 1536 + jj * 128 + ptid;                                      \
            int c = fi / 192; int j = fi - c * 192;                                      \
            int p = j / 3; int a4 = (j - p * 3) * 4;                                     \
            ushort4 pk = make_ushort4(f2bf(src[jj].x), f2bf(src[jj].y),                  \
                                      f2bf(src[jj].z), f2bf(src[jj].w));                 \
            *(ushort4*)&Bs[bw][p][c * A_ + a4] = pk;                                     \
          } }
    #define PSTAGE(s, bw)                                                                \
        { float4 pfA[12], pfB[12];                                                       \
          PLOADR(pfA, s, 0); PLOADR(pfB, s, 1);                                          \
          PWRITE(pfA, bw, 0);                                                            \
          PLOADR(pfA, s, 2);                                                             \
          PWRITE(pfB, bw, 1);                                                            \
          PLOADR(pfB, s, 3);                                                             \
          PWRITE(pfA, bw, 2);                                                            \
          PWRITE(pfB, bw, 3);                                                            \
          _Pragma("unroll")                                                              \
          for (int t = 0; t < 16; t++) {                                                 \
            int idx = t * 128 + ptid; int p = idx >> 5; int d = idx & 31;                \
            const float* kv = &kpoS[(d * K_ + (s)) * 3];                                 \
            float sd = mdS[p][0] * kv[0] + mdS[p][1] * kv[1] + mdS[p][2] * kv[2];        \
            pwS[bw][p][d] = fmaxf(sd, 0.f);                                              \
          } }

    // ---- consumer A-fragment loads (WT global, L2-hot), triple-buffered
    const unsigned short* awbase = WT + (size_t)(wid * 64 + rowm) * CA_ + quad * 8;
    #define LOAD_A(dst, kk, ch)                                                          \
        { const unsigned short* ap = awbase + (size_t)(kk) * (DR_ * CA_) + (ch) * 32;    \
          _Pragma("unroll")                                                              \
          for (int mt = 0; mt < 4; mt++) dst[mt] = *(const short8*)(ap + mt * 16 * CA_); }

    // small tables (whole block)
    for (int i = tid; i < PT_ * 3; i += 512) {
        int p = i / 3, c = i % 3;
        mdS[p][c] = md[((size_t)b * P_ + p0 + p) * 3 + c];
    }
    for (int i = tid; i < C2_ * K_ * 3; i += 512) kpoS[i] = kpo[i];
    for (int i = tid; i < DR_; i += 512) biasS[i] = be[i];
    __syncthreads();   // tables visible (producers read mdS/kpoS)

    floatx4 acc_o[4][4];
    floatx4 acc_k[4][4];
    short8 abuf[3][4];
    const int ptid = tid - 384;   // valid for producers only

    if (consumer) {
        #pragma unroll
        for (int mt = 0; mt < 4; mt++)
            #pragma unroll
            for (int nt = 0; nt < 4; nt++) { acc_o[mt][nt] = (floatx4)0.f; acc_k[mt][nt] = (floatx4)0.f; }
        LOAD_A(abuf[0], 0, 0);
        LOAD_A(abuf[1], 0, 1);
    } else {
        PSTAGE(0, 0);
    }
    __syncthreads();   // Bs[0]/pwS[0] published

    for (int k = 0; k < K_; k++) {
        const int buf = k & 1;
        if (consumer) {
            #pragma unroll
            for (int ch = 0; ch < 12; ch++) {
                if (ch < 10)          { LOAD_A(abuf[(ch + 2) % 3], k, ch + 2); }
                else if (k + 1 < K_)  { LOAD_A(abuf[(ch + 2) % 3], k + 1, ch - 10); }
                short8 bfr[4];
                #pragma unroll
                for (int nt = 0; nt < 4; nt++)
                    bfr[nt] = *(const short8*)(&Bs[buf][nt * 16 + rowm][ch * 32 + quad * 8]);
                const short8* af = abuf[ch % 3];
                #pragma unroll
                for (int mt = 0; mt < 4; mt++)
                    #pragma unroll
                    for (int nt = 0; nt < 4; nt++)
                        acc_k[mt][nt] = __builtin_amdgcn_mfma_f32_16x16x32_bf16(af[mt], bfr[nt], acc_k[mt][nt], 0, 0, 0);
            }
            // epilogue-k: acc_o += pw[p,d] * acc_k   (d-calc is k-invariant -> LICM)
            #pragma unroll
            for (int mt = 0; mt < 4; mt++) {
                int drb = wid * 64 + mt * 16 + quad * 4;
                #pragma unroll
                for (int reg = 0; reg < 4; reg++) {
                    int d = (drb + reg) / 12;
                    #pragma unroll
                    for (int nt = 0; nt < 4; nt++) {
                        float pv = pwS[buf][nt * 16 + rowm][d];
                        acc_o[mt][nt][reg] += pv * acc_k[mt][nt][reg];
                        acc_k[mt][nt][reg] = 0.f;
                    }
                }
            }
        } else {
            if (k + 1 < K_) { PSTAGE(k + 1, (k + 1) & 1); }
        }
        __syncthreads();   // swap buffers
    }

    // ---- final: relu(acc_o + bias_eff) -> out[b,d,p,r] ----
    if (consumer) {
        #pragma unroll
        for (int mt = 0; mt < 4; mt++) {
            #pragma unroll
            for (int reg = 0; reg < 4; reg++) {
                int dr = wid * 64 + mt * 16 + quad * 4 + reg;
                int d = dr / 12, r = dr - d * 12;
                #pragma unroll
                for (int nt = 0; nt < 4; nt++) {
                    int p = p0 + nt * 16 + rowm;
                    float v = acc_o[mt][nt][reg] + biasS[dr];
                    out[(((size_t)b * C2_ + d) * P_ + p) * A_ + r] = fmaxf(v, 0.f);
                }
            }
        }
    }
}

// ---------------- launcher ----------------
extern "C" void kernel_launch(void* const* d_in, const int* in_sizes, int n_in,
                              void* d_out, int out_size, void* d_ws, size_t ws_size,
                              hipStream_t stream) {
    const int*   nbr     = (const int*)d_in[0];
    const float* verts   = (const float*)d_in[1];
    const float* fm      = (const float*)d_in[2];
    const float* W       = (const float*)d_in[3];
    const float* bias    = (const float*)d_in[4];
    const float* kpw     = (const float*)d_in[5];
    const float* vs      = (const float*)d_in[6];
    const int*   idx_map = (const int*)d_in[7];
    const int*   tivr    = (const int*)d_in[8];
    const int*   tir     = (const int*)d_in[9];
    const int*   lvl     = (const int*)d_in[10];
    float* out = (float*)d_out;

    char* ws = (char*)d_ws;
    unsigned short* WT2 = (unsigned short*)ws;            // 13*384*384*2 = 3,833,856 B
    float* md_ws  = (float*)(ws + 4000000);               // 196,608 B
    float* kpo_ws = (float*)(ws + 4200000);               // 4,992 B
    float* be_ws  = (float*)(ws + 4210000);               // 1,536 B

    {
        const int TOT = K_ * DR_ * CA_;                   // 1,916,928
        build_wt<<<(TOT + 255) / 256, 256, 0, stream>>>(W, kpw, idx_map, tivr, tir, WT2);
    }
    build_md<<<(B_ * P_) / 256, 256, 0, stream>>>(nbr, verts, md_ws);
    build_kpo<<<7, 64, 0, stream>>>(kpw, idx_map, vs, kpo_ws);
    build_be<<<6, 64, 0, stream>>>(bias, lvl, tivr, be_ws);

    main_gemm<<<B_ * (P_ / PT_), 512, 0, stream>>>(fm, WT2, md_ws, kpo_ws, be_ws, out);
}